// Round 1
// baseline (1285.994 us; speedup 1.0000x reference)
//
#include <hip/hip_runtime.h>
#include <math.h>

#define NN 50000
#define NE 500000
#define NREL 4
#define D 128
static constexpr float BN_EPS = 1e-5f;

// ---------------- utility ----------------
__global__ __launch_bounds__(256) void k_zero(int* __restrict__ p, int n) {
    int i = blockIdx.x * blockDim.x + threadIdx.x;
    if (i < n) p[i] = 0;
}

// ---------------- degree count ----------------
// edge_index layout: [NREL][2][NE]; ei[r][0][e]=src, ei[r][1][e]=dst
__global__ __launch_bounds__(256) void k_count(const int* __restrict__ ei, int* __restrict__ deg) {
    int e = blockIdx.x * blockDim.x + threadIdx.x;
    int r = blockIdx.y;
    if (e < NE) {
        int dst = ei[r * 2 * NE + NE + e];
        atomicAdd(&deg[r * NN + dst], 1);
    }
}

__global__ __launch_bounds__(256) void k_dinv(const int* __restrict__ deg, float* __restrict__ dinv) {
    int i = blockIdx.x * blockDim.x + threadIdx.x;
    int r = blockIdx.y;
    if (i < NN) dinv[r * NN + i] = rsqrtf((float)(deg[r * NN + i] + 1)); // +1 self loop
}

// ---------------- exclusive scan (one block per relation) ----------------
__global__ __launch_bounds__(1024) void k_scan(const int* __restrict__ deg, int* __restrict__ rowp,
                                               int* __restrict__ fill) {
    int r = blockIdx.x;
    __shared__ int sdata[1024];
    __shared__ int s_off;
    int tid = threadIdx.x;
    if (tid == 0) s_off = 0;
    __syncthreads();
    for (int base = 0; base < NN; base += 1024) {
        int i = base + tid;
        int v = (i < NN) ? deg[r * NN + i] : 0;
        sdata[tid] = v;
        __syncthreads();
        for (int d = 1; d < 1024; d <<= 1) {
            int t = (tid >= d) ? sdata[tid - d] : 0;
            __syncthreads();
            sdata[tid] += t;
            __syncthreads();
        }
        int incl = sdata[tid];
        int excl = incl - v;
        if (i < NN) {
            int rp = s_off + excl;
            rowp[r * (NN + 1) + i] = rp;
            fill[r * NN + i] = rp;
        }
        __syncthreads();
        if (tid == 1023) s_off += sdata[1023];
        __syncthreads();
    }
    if (tid == 0) rowp[r * (NN + 1) + NN] = s_off;
}

// ---------------- CSR fill ----------------
__global__ __launch_bounds__(256) void k_fill(const int* __restrict__ ei, int* __restrict__ fill,
                                              int* __restrict__ csr) {
    int e = blockIdx.x * blockDim.x + threadIdx.x;
    int r = blockIdx.y;
    if (e < NE) {
        int src = ei[r * 2 * NE + e];
        int dst = ei[r * 2 * NE + NE + e];
        int pos = atomicAdd(&fill[r * NN + dst], 1);
        csr[r * NE + pos] = src;
    }
}

// ---------------- init H with sum of 4 relation biases ----------------
__global__ __launch_bounds__(256) void k_bias_init(const float* __restrict__ b, float* __restrict__ H) {
    int i = blockIdx.x * blockDim.x + threadIdx.x;
    if (i < NN * D) {
        int j = i & (D - 1);
        H[i] = b[j] + b[D + j] + b[2 * D + j] + b[3 * D + j];
    }
}

// ---------------- fp32 GEMM: C[NN,D] = op(A)[NN,D] @ B[D,D] ----------------
template <bool RELU_A>
__global__ __launch_bounds__(256) void k_gemm(const float* __restrict__ A, const float* __restrict__ B,
                                              float* __restrict__ C) {
    __shared__ float As[16][68]; // [k][m], padded stride 68 to soften store conflicts
    __shared__ float Bs[16][64]; // [k][n]
    int tid = threadIdx.x;
    int tx = tid & 15, ty = tid >> 4;
    int m0 = blockIdx.y * 64, n0 = blockIdx.x * 64;
    float c[4][4] = {};
    for (int k0 = 0; k0 < D; k0 += 16) {
        { // A tile -> transposed LDS
            int row = tid >> 2;
            int c4 = (tid & 3) * 4;
            int gr = m0 + row;
            float4 v = make_float4(0.f, 0.f, 0.f, 0.f);
            if (gr < NN) v = *(const float4*)(A + (size_t)gr * D + k0 + c4);
            if (RELU_A) {
                v.x = fmaxf(v.x, 0.f); v.y = fmaxf(v.y, 0.f);
                v.z = fmaxf(v.z, 0.f); v.w = fmaxf(v.w, 0.f);
            }
            As[c4 + 0][row] = v.x; As[c4 + 1][row] = v.y;
            As[c4 + 2][row] = v.z; As[c4 + 3][row] = v.w;
        }
        { // B tile
            int rB = tid >> 4;
            int cB = (tid & 15) * 4;
            float4 v = *(const float4*)(B + (size_t)(k0 + rB) * D + n0 + cB);
            *(float4*)(&Bs[rB][cB]) = v;
        }
        __syncthreads();
#pragma unroll
        for (int kk = 0; kk < 16; kk++) {
            float4 av = *(const float4*)(&As[kk][ty * 4]);
            float4 bv = *(const float4*)(&Bs[kk][tx * 4]);
            float a[4] = {av.x, av.y, av.z, av.w};
            float b[4] = {bv.x, bv.y, bv.z, bv.w};
#pragma unroll
            for (int i = 0; i < 4; i++)
#pragma unroll
                for (int j = 0; j < 4; j++) c[i][j] = fmaf(a[i], b[j], c[i][j]);
        }
        __syncthreads();
    }
#pragma unroll
    for (int i = 0; i < 4; i++) {
        int gr = m0 + ty * 4 + i;
        if (gr < NN)
            *(float4*)(C + (size_t)gr * D + n0 + tx * 4) =
                make_float4(c[i][0], c[i][1], c[i][2], c[i][3]);
    }
}

// ---------------- per-relation gather aggregation ----------------
// H[n] += dinv[n] * ( sum_{src in in(n)} T[src]*dinv[src] + T[n]*dinv[n] )
__global__ __launch_bounds__(256) void k_aggregate(const float* __restrict__ T,
                                                   const int* __restrict__ rowp,
                                                   const int* __restrict__ csr,
                                                   const float* __restrict__ dinv,
                                                   float* __restrict__ H) {
    int lane = threadIdx.x & 63;
    int wave = threadIdx.x >> 6;
    int n = blockIdx.x * 4 + wave;
    if (n >= NN) return;
    int start = rowp[n], end = rowp[n + 1];
    int col = lane * 2;
    float ax = 0.f, ay = 0.f;
    for (int e = start; e < end; e++) {
        int s = csr[e];
        float w = dinv[s];
        float2 v = *(const float2*)(T + (size_t)s * D + col);
        ax = fmaf(v.x, w, ax);
        ay = fmaf(v.y, w, ay);
    }
    float wn = dinv[n];
    float2 vs = *(const float2*)(T + (size_t)n * D + col);
    ax = fmaf(vs.x, wn, ax);
    ay = fmaf(vs.y, wn, ay);
    float2 h = *(float2*)(H + (size_t)n * D + col);
    h.x = fmaf(ax, wn, h.x);
    h.y = fmaf(ay, wn, h.y);
    *(float2*)(H + (size_t)n * D + col) = h;
}

// ---------------- BN statistics over relu(H2) ----------------
__global__ __launch_bounds__(256) void k_bn_stats(const float* __restrict__ H2, float* __restrict__ sums) {
    int tid = threadIdx.x;
    int c = tid & 127, g = tid >> 7;
    int row0 = blockIdx.x * 256;
    int rend = min(row0 + 256, NN);
    float s = 0.f, q = 0.f;
    for (int r = row0 + g; r < rend; r += 2) {
        float v = fmaxf(H2[(size_t)r * D + c], 0.f);
        s += v;
        q += v * v;
    }
    __shared__ float sb[256], qb[256];
    sb[tid] = s; qb[tid] = q;
    __syncthreads();
    if (g == 0) {
        atomicAdd(&sums[c], sb[c] + sb[c + 128]);
        atomicAdd(&sums[D + c], qb[c] + qb[c + 128]);
    }
}

__global__ __launch_bounds__(128) void k_bn_final(const float* __restrict__ sums,
                                                  const float* __restrict__ gamma,
                                                  const float* __restrict__ beta,
                                                  float* __restrict__ bnp) {
    int c = threadIdx.x;
    if (c < D) {
        float mean = sums[c] / (float)NN;
        float var = sums[D + c] / (float)NN - mean * mean;
        float sc = gamma[c] * rsqrtf(var + BN_EPS);
        bnp[c] = sc;
        bnp[D + c] = beta[c] - mean * sc;
    }
}

// ---------------- fused BN + lin1 + relu + lin2 ----------------
__global__ __launch_bounds__(256) void k_final(const float* __restrict__ H2, const float* __restrict__ bnp,
                                               const float* __restrict__ W1, const float* __restrict__ b1,
                                               const float* __restrict__ W2, const float* __restrict__ b2,
                                               float* __restrict__ out) {
    __shared__ float W1s[D * D]; // 64 KB
    __shared__ float hnS[2][D];
    __shared__ float part[2][2][2];
    int tid = threadIdx.x;
    for (int i = tid * 4; i < D * D; i += 1024) *(float4*)(W1s + i) = *(const float4*)(W1 + i);
    int g = tid >> 7, j = tid & 127;
    float sc = bnp[j], sh = bnp[D + j], bb = b1[j];
    float w20 = W2[j * 2], w21 = W2[j * 2 + 1];
    float ob0 = b2[0], ob1 = b2[1];
    __syncthreads();
    for (int n = blockIdx.x * 2 + g; n < NN; n += gridDim.x * 2) {
        hnS[g][j] = fmaxf(H2[(size_t)n * D + j], 0.f) * sc + sh;
        __syncthreads();
        float a0 = 0.f, a1 = 0.f, a2 = 0.f, a3 = 0.f;
#pragma unroll
        for (int i = 0; i < D; i += 4) {
            a0 = fmaf(hnS[g][i + 0], W1s[(i + 0) * D + j], a0);
            a1 = fmaf(hnS[g][i + 1], W1s[(i + 1) * D + j], a1);
            a2 = fmaf(hnS[g][i + 2], W1s[(i + 2) * D + j], a2);
            a3 = fmaf(hnS[g][i + 3], W1s[(i + 3) * D + j], a3);
        }
        float y = fmaxf(bb + ((a0 + a1) + (a2 + a3)), 0.f);
        float p0 = y * w20, p1 = y * w21;
        for (int off = 32; off > 0; off >>= 1) {
            p0 += __shfl_down(p0, off);
            p1 += __shfl_down(p1, off);
        }
        int wg = j >> 6;
        if ((j & 63) == 0) { part[g][wg][0] = p0; part[g][wg][1] = p1; }
        __syncthreads();
        if (j == 0) {
            out[(size_t)n * 2 + 0] = part[g][0][0] + part[g][1][0] + ob0;
            out[(size_t)n * 2 + 1] = part[g][0][1] + part[g][1][1] + ob1;
        }
        __syncthreads();
    }
}

extern "C" void kernel_launch(void* const* d_in, const int* in_sizes, int n_in,
                              void* d_out, int out_size, void* d_ws, size_t ws_size,
                              hipStream_t stream) {
    const float* x = (const float*)d_in[0];
    const int* ei = (const int*)d_in[1];
    const float* W1 = (const float*)d_in[2];
    const float* b1 = (const float*)d_in[3];
    const float* W2 = (const float*)d_in[4];
    const float* b2 = (const float*)d_in[5];
    const float* gamma = (const float*)d_in[6];
    const float* beta = (const float*)d_in[7];
    const float* l1W = (const float*)d_in[8];
    const float* l1b = (const float*)d_in[9];
    const float* l2W = (const float*)d_in[10];
    const float* l2b = (const float*)d_in[11];
    float* out = (float*)d_out;

    char* ws = (char*)d_ws;
    size_t off = 0;
    auto alloc = [&](size_t bytes) {
        void* p = ws + off;
        off += (bytes + 255) & ~(size_t)255;
        return p;
    };
    int* deg = (int*)alloc((size_t)NREL * NN * sizeof(int));
    float* dinv = (float*)alloc((size_t)NREL * NN * sizeof(float));
    int* rowp = (int*)alloc((size_t)NREL * (NN + 1) * sizeof(int));
    int* fill = (int*)alloc((size_t)NREL * NN * sizeof(int));
    int* csr = (int*)alloc((size_t)NREL * NE * sizeof(int));
    float* T = (float*)alloc((size_t)NN * D * sizeof(float));
    float* H1 = (float*)alloc((size_t)NN * D * sizeof(float));
    float* H2 = (float*)alloc((size_t)NN * D * sizeof(float));
    float* bnsum = (float*)alloc(2 * D * sizeof(float));
    float* bnp = (float*)alloc(2 * D * sizeof(float));

    // graph preprocessing (per launch; inputs re-poisoned each call)
    k_zero<<<(NREL * NN + 255) / 256, 256, 0, stream>>>(deg, NREL * NN);
    k_zero<<<1, 256, 0, stream>>>((int*)bnsum, 2 * D);
    dim3 egrid((NE + 255) / 256, NREL);
    k_count<<<egrid, 256, 0, stream>>>(ei, deg);
    dim3 ngrid((NN + 255) / 256, NREL);
    k_dinv<<<ngrid, 256, 0, stream>>>(deg, dinv);
    k_scan<<<NREL, 1024, 0, stream>>>(deg, rowp, fill);
    k_fill<<<egrid, 256, 0, stream>>>(ei, fill, csr);

    dim3 ggrid(D / 64, (NN + 63) / 64);
    dim3 agrid((NN + 3) / 4);

    // layer 1
    k_bias_init<<<(NN * D + 255) / 256, 256, 0, stream>>>(b1, H1);
    for (int r = 0; r < NREL; r++) {
        k_gemm<false><<<ggrid, 256, 0, stream>>>(x, W1 + (size_t)r * D * D, T);
        k_aggregate<<<agrid, 256, 0, stream>>>(T, rowp + (size_t)r * (NN + 1), csr + (size_t)r * NE,
                                               dinv + (size_t)r * NN, H1);
    }
    // layer 2 (relu of H1 fused into GEMM A-read)
    k_bias_init<<<(NN * D + 255) / 256, 256, 0, stream>>>(b2, H2);
    for (int r = 0; r < NREL; r++) {
        k_gemm<true><<<ggrid, 256, 0, stream>>>(H1, W2 + (size_t)r * D * D, T);
        k_aggregate<<<agrid, 256, 0, stream>>>(T, rowp + (size_t)r * (NN + 1), csr + (size_t)r * NE,
                                               dinv + (size_t)r * NN, H2);
    }
    // BatchNorm over relu(H2) + fused MLP head
    k_bn_stats<<<(NN + 255) / 256, 256, 0, stream>>>(H2, bnsum);
    k_bn_final<<<1, 128, 0, stream>>>(bnsum, gamma, beta, bnp);
    k_final<<<2048, 256, 0, stream>>>(H2, bnp, l1W, l1b, l2W, l2b, out);
}